// Round 1
// baseline (870.882 us; speedup 1.0000x reference)
//
#include <hip/hip_runtime.h>

#define HH 256   // H
#define BB 64    // B
#define KK 32    // K
#define LL 64    // L

typedef __bf16 bf16_t;
typedef __attribute__((ext_vector_type(8))) __bf16 bf16x8;
typedef __attribute__((ext_vector_type(4))) float f32x4;

// ---- load 8 contiguous f32, convert to bf16x8 (A-fragment) ----
__device__ __forceinline__ bf16x8 ld_a8(const float* __restrict__ p) {
  const f32x4* q = (const f32x4*)p;
  f32x4 a = q[0], b = q[1];
  bf16x8 r;
  r[0] = (__bf16)a[0]; r[1] = (__bf16)a[1]; r[2] = (__bf16)a[2]; r[3] = (__bf16)a[3];
  r[4] = (__bf16)b[0]; r[5] = (__bf16)b[1]; r[6] = (__bf16)b[2]; r[7] = (__bf16)b[3];
  return r;
}

// acc[mtile][ntile] += A(32x256, f32 row-major) * B(64 rows of W, bf16 row-major)^T
// A-frag: row = lane&15 (+16 for mtile1), k = ks*32 + (lane>>4)*8 + j
// B-frag: out-col = nt*16 + (lane&15), same k pattern
template<int LDB>
__device__ __forceinline__ void mm_f32A(const float* __restrict__ A,
                                        const bf16_t* __restrict__ B,
                                        f32x4 acc[2][4], int lane) {
  const int c = lane & 15, g = lane >> 4;
#pragma unroll
  for (int ks = 0; ks < 8; ++ks) {
    const int ko = ks * 32 + g * 8;
    bf16x8 a0 = ld_a8(A + c * HH + ko);
    bf16x8 a1 = ld_a8(A + (16 + c) * HH + ko);
#pragma unroll
    for (int nt = 0; nt < 4; ++nt) {
      bf16x8 bb = *(const bf16x8*)(B + (nt * 16 + c) * LDB + ko);
      acc[0][nt] = __builtin_amdgcn_mfma_f32_16x16x32_bf16(a0, bb, acc[0][nt], 0, 0, 0);
      acc[1][nt] = __builtin_amdgcn_mfma_f32_16x16x32_bf16(a1, bb, acc[1][nt], 0, 0, 0);
    }
  }
}

// relu(acc) -> swizzled bf16 LDS tile (32 rows x 256 cols, 512B/row, XOR bits4-6)
__device__ __forceinline__ void store_pre(const f32x4 acc[2][4], bf16_t* lds,
                                          int colw, int lane) {
  const int c = lane & 15, g = lane >> 4;
#pragma unroll
  for (int m = 0; m < 2; ++m)
#pragma unroll
    for (int nt = 0; nt < 4; ++nt)
#pragma unroll
      for (int rr = 0; rr < 4; ++rr) {
        int row = m * 16 + g * 4 + rr;
        int col = colw + nt * 16 + c;
        float v = acc[m][nt][rr];
        v = v > 0.f ? v : 0.f;
        int off = row * 512 + ((col * 2) ^ ((row & 7) << 4));
        *(bf16_t*)((char*)lds + off) = (__bf16)v;
      }
}

// acc += LDS-pre(32x256 bf16, swizzled) * B^T
template<int LDB>
__device__ __forceinline__ void mm_ldsA(const bf16_t* lds,
                                        const bf16_t* __restrict__ B,
                                        f32x4 acc[2][4], int lane) {
  const int c = lane & 15, g = lane >> 4;
#pragma unroll
  for (int ks = 0; ks < 8; ++ks) {
    const int kbyte = (ks * 32 + g * 8) * 2;
    const int swz = (c & 7) << 4;  // (row&7) == (c&7) for rows c and 16+c
    bf16x8 a0 = *(const bf16x8*)((const char*)lds + c * 512 + (kbyte ^ swz));
    bf16x8 a1 = *(const bf16x8*)((const char*)lds + (16 + c) * 512 + (kbyte ^ swz));
#pragma unroll
    for (int nt = 0; nt < 4; ++nt) {
      bf16x8 bb = *(const bf16x8*)(B + (nt * 16 + c) * LDB + ks * 32 + g * 8);
      acc[0][nt] = __builtin_amdgcn_mfma_f32_16x16x32_bf16(a0, bb, acc[0][nt], 0, 0, 0);
      acc[1][nt] = __builtin_amdgcn_mfma_f32_16x16x32_bf16(a1, bb, acc[1][nt], 0, 0, 0);
    }
  }
}

// ---------------- prep: weights f32->bf16, m_ue := a2u_b2 broadcast ----------------
__global__ __launch_bounds__(256) void prep_kernel(
    const float* w0, const float* w1, const float* w2, const float* w3,
    const float* w4, const float* w5, const float* w6, const float* w7,
    const float* w8, const float* w9, const float* a2u_b2,
    bf16_t* wb, float* m_ue) {
  int i = blockIdx.x * 256 + threadIdx.x;
  if (i < 1441792) {
    const float* s; int o;
    if      (i < 131072)  { s = w0; o = i; }
    else if (i < 196608)  { s = w1; o = i - 131072; }
    else if (i < 327680)  { s = w2; o = i - 196608; }
    else if (i < 393216)  { s = w3; o = i - 327680; }
    else if (i < 589824)  { s = w4; o = i - 393216; }
    else if (i < 786432)  { s = w5; o = i - 589824; }
    else if (i < 983040)  { s = w6; o = i - 786432; }
    else if (i < 1179648) { s = w7; o = i - 983040; }
    else if (i < 1376256) { s = w8; o = i - 1179648; }
    else                  { s = w9; o = i - 1376256; }
    wb[i] = (__bf16)s[o];
  } else {
    int j = i - 1441792;
    m_ue[j] = a2u_b2[j & 255];
  }
}

// ---------------- generic projection: out(rows x 256) = X * W^T + bias ----------------
template<int LDW>
__global__ __launch_bounds__(256) void proj_kernel(
    const float* __restrict__ X, const bf16_t* __restrict__ W,
    const float* __restrict__ bias, float* __restrict__ out) {
  const int row0 = blockIdx.x * 32;
  const int tid = threadIdx.x, w = tid >> 6, lane = tid & 63;
  const int colw = w * 64, c = lane & 15, g = lane >> 4;
  f32x4 acc[2][4];
#pragma unroll
  for (int nt = 0; nt < 4; ++nt) {
    float bv = bias ? bias[colw + nt * 16 + c] : 0.f;
    f32x4 t = {bv, bv, bv, bv};
    acc[0][nt] = t; acc[1][nt] = t;
  }
  mm_f32A<LDW>(X + (size_t)row0 * HH, W + (size_t)colw * LDW, acc, lane);
#pragma unroll
  for (int m = 0; m < 2; ++m)
#pragma unroll
    for (int nt = 0; nt < 4; ++nt)
#pragma unroll
      for (int rr = 0; rr < 4; ++rr) {
        int row = row0 + m * 16 + g * 4 + rr;
        out[(size_t)row * HH + colw + nt * 16 + c] = acc[m][nt][rr];
      }
}

// ---------------- phase A: both message MLPs + mean reductions ----------------
__global__ __launch_bounds__(256) void phaseA_kernel(
    const float* __restrict__ e, const float* __restrict__ p_ap,
    const float* __restrict__ p_ue,
    const bf16_t* __restrict__ wa1e, const bf16_t* __restrict__ wa2,
    const bf16_t* __restrict__ wu1e, const bf16_t* __restrict__ wu2,
    const float* __restrict__ u2a_b2,
    float* __restrict__ m_ue, float* __restrict__ m_ap) {
  __shared__ bf16_t lds[32 * 256];
  const int blk = blockIdx.x;
  const int b = blk >> 4, lc = blk & 15;
  const int tid = threadIdx.x, w = tid >> 6, lane = tid & 63;
  const int colw = w * 64, c = lane & 15, g = lane >> 4;

  f32x4 accU[2][4];
  const f32x4 z4 = {0.f, 0.f, 0.f, 0.f};
#pragma unroll
  for (int m = 0; m < 2; ++m)
#pragma unroll
    for (int nt = 0; nt < 4; ++nt) accU[m][nt] = z4;

  for (int li = 0; li < 4; ++li) {
    const int l = lc * 4 + li;
    const float* E = e + (size_t)((b * LL + l) * KK) * HH;

    // --- AP->UE: pre = E*Wa1e^T + p_ap (row-invariant) ---
    f32x4 acc[2][4];
#pragma unroll
    for (int nt = 0; nt < 4; ++nt) {
      float pv = p_ap[(size_t)(b * LL + l) * HH + colw + nt * 16 + c];
      f32x4 t = {pv, pv, pv, pv};
      acc[0][nt] = t; acc[1][nt] = t;
    }
    mm_f32A<512>(E, wa1e + (size_t)colw * 512, acc, lane);
    store_pre(acc, lds, colw, lane);
    __syncthreads();
    mm_ldsA<256>(lds, wa2 + (size_t)colw * 256, accU, lane);  // accumulate over l in C
    __syncthreads();

    // --- UE->AP: pre = E*Wu1e^T + p_ue (row-varying) ---
#pragma unroll
    for (int m = 0; m < 2; ++m)
#pragma unroll
      for (int nt = 0; nt < 4; ++nt)
#pragma unroll
        for (int rr = 0; rr < 4; ++rr)
          acc[m][nt][rr] = p_ue[(size_t)(b * KK + m * 16 + g * 4 + rr) * HH + colw + nt * 16 + c];
    mm_f32A<512>(E, wu1e + (size_t)colw * 512, acc, lane);
    store_pre(acc, lds, colw, lane);
    __syncthreads();
    f32x4 accV[2][4];
#pragma unroll
    for (int m = 0; m < 2; ++m)
#pragma unroll
      for (int nt = 0; nt < 4; ++nt) accV[m][nt] = z4;
    mm_ldsA<256>(lds, wu2 + (size_t)colw * 256, accV, lane);

    // row-reduce (over the 32 UE neighbors) -> m_ap[b,l,:]
#pragma unroll
    for (int nt = 0; nt < 4; ++nt) {
      float s = 0.f;
#pragma unroll
      for (int m = 0; m < 2; ++m)
#pragma unroll
        for (int rr = 0; rr < 4; ++rr) s += accV[m][nt][rr];
      s += __shfl_xor(s, 16);
      s += __shfl_xor(s, 32);
      if (lane < 16) {
        int col = colw + nt * 16 + lane;
        m_ap[(size_t)(b * LL + l) * HH + col] = s * (1.0f / KK) + u2a_b2[col];
      }
    }
    __syncthreads();
  }

  // scatter a2u accumulation (sum over 4 l's) / L into m_ue
#pragma unroll
  for (int m = 0; m < 2; ++m)
#pragma unroll
    for (int nt = 0; nt < 4; ++nt)
#pragma unroll
      for (int rr = 0; rr < 4; ++rr) {
        int krow = m * 16 + g * 4 + rr;
        int col = colw + nt * 16 + c;
        atomicAdd(&m_ue[(size_t)(b * KK + krow) * HH + col], accU[m][nt][rr] * (1.0f / LL));
      }
}

// ---------------- GRU: h_new = (1-z)*n + z*h ----------------
__global__ __launch_bounds__(256) void gru_kernel(
    const float* __restrict__ x, const float* __restrict__ h,
    const bf16_t* __restrict__ wih, const bf16_t* __restrict__ whh,
    const float* __restrict__ bih, const float* __restrict__ bhh,
    float* __restrict__ hout) {
  const int row0 = blockIdx.x * 32;
  const int tid = threadIdx.x, w = tid >> 6, lane = tid & 63;
  const int colw = w * 64, c = lane & 15, g = lane >> 4;
  f32x4 aR[2][4], aZ[2][4], aN[2][4], aHN[2][4];
#pragma unroll
  for (int nt = 0; nt < 4; ++nt) {
    int col = colw + nt * 16 + c;
    float vR = bih[col] + bhh[col];
    float vZ = bih[256 + col] + bhh[256 + col];
    float vN = bih[512 + col];
    float vH = bhh[512 + col];
    f32x4 tR = {vR, vR, vR, vR}, tZ = {vZ, vZ, vZ, vZ};
    f32x4 tN = {vN, vN, vN, vN}, tH = {vH, vH, vH, vH};
    aR[0][nt] = tR; aR[1][nt] = tR;
    aZ[0][nt] = tZ; aZ[1][nt] = tZ;
    aN[0][nt] = tN; aN[1][nt] = tN;
    aHN[0][nt] = tH; aHN[1][nt] = tH;
  }
  const float* X = x + (size_t)row0 * HH;
  const float* Hp = h + (size_t)row0 * HH;
  mm_f32A<256>(X,  wih + (size_t)(0   + colw) * 256, aR, lane);
  mm_f32A<256>(Hp, whh + (size_t)(0   + colw) * 256, aR, lane);
  mm_f32A<256>(X,  wih + (size_t)(256 + colw) * 256, aZ, lane);
  mm_f32A<256>(Hp, whh + (size_t)(256 + colw) * 256, aZ, lane);
  mm_f32A<256>(X,  wih + (size_t)(512 + colw) * 256, aN, lane);
  mm_f32A<256>(Hp, whh + (size_t)(512 + colw) * 256, aHN, lane);
#pragma unroll
  for (int m = 0; m < 2; ++m)
#pragma unroll
    for (int nt = 0; nt < 4; ++nt)
#pragma unroll
      for (int rr = 0; rr < 4; ++rr) {
        int row = row0 + m * 16 + g * 4 + rr;
        int col = colw + nt * 16 + c;
        float rg = 1.f / (1.f + __expf(-aR[m][nt][rr]));
        float zg = 1.f / (1.f + __expf(-aZ[m][nt][rr]));
        float t = aN[m][nt][rr] + rg * aHN[m][nt][rr];
        t = fminf(fmaxf(t, -15.f), 15.f);
        float ex = __expf(-2.f * t);
        float ng = (1.f - ex) / (1.f + ex);
        float ho = h[(size_t)row * HH + col];
        hout[(size_t)row * HH + col] = (1.f - zg) * ng + zg * ho;
      }
}

// ---------------- phase C: edge update ----------------
__global__ __launch_bounds__(256) void phaseC_kernel(
    const float* __restrict__ e, const float* __restrict__ q_ue,
    const float* __restrict__ q_ap,
    const bf16_t* __restrict__ wed1e, const bf16_t* __restrict__ wed2,
    const float* __restrict__ ed_b2, float* __restrict__ e_new) {
  __shared__ bf16_t lds[32 * 256];
  const int blk = blockIdx.x;
  const int b = blk >> 6, l = blk & 63;
  const int tid = threadIdx.x, w = tid >> 6, lane = tid & 63;
  const int colw = w * 64, c = lane & 15, g = lane >> 4;
  const float* E = e + (size_t)((b * LL + l) * KK) * HH;

  f32x4 acc[2][4];
#pragma unroll
  for (int nt = 0; nt < 4; ++nt) {
    int col = colw + nt * 16 + c;
    float qa = q_ap[(size_t)(b * LL + l) * HH + col];
#pragma unroll
    for (int m = 0; m < 2; ++m)
#pragma unroll
      for (int rr = 0; rr < 4; ++rr) {
        int krow = m * 16 + g * 4 + rr;
        acc[m][nt][rr] = qa + q_ue[(size_t)(b * KK + krow) * HH + col];
      }
  }
  mm_f32A<768>(E, wed1e + (size_t)colw * 768, acc, lane);
  store_pre(acc, lds, colw, lane);
  __syncthreads();

  f32x4 acc2[2][4];
#pragma unroll
  for (int nt = 0; nt < 4; ++nt) {
    float bv = ed_b2[colw + nt * 16 + c];
    f32x4 t = {bv, bv, bv, bv};
    acc2[0][nt] = t; acc2[1][nt] = t;
  }
  mm_ldsA<256>(lds, wed2 + (size_t)colw * 256, acc2, lane);
#pragma unroll
  for (int m = 0; m < 2; ++m)
#pragma unroll
    for (int nt = 0; nt < 4; ++nt)
#pragma unroll
      for (int rr = 0; rr < 4; ++rr) {
        int row = m * 16 + g * 4 + rr;
        int col = colw + nt * 16 + c;
        e_new[(size_t)((b * LL + l) * KK + row) * HH + col] = acc2[m][nt][rr];
      }
}

extern "C" void kernel_launch(void* const* d_in, const int* in_sizes, int n_in,
                              void* d_out, int out_size, void* d_ws, size_t ws_size,
                              hipStream_t stream) {
  const float* h_ue   = (const float*)d_in[0];
  const float* h_ap   = (const float*)d_in[1];
  const float* e      = (const float*)d_in[2];
  const float* a2u_w1 = (const float*)d_in[3];
  const float* a2u_b1 = (const float*)d_in[4];
  const float* a2u_w2 = (const float*)d_in[5];
  const float* a2u_b2 = (const float*)d_in[6];
  const float* u2a_w1 = (const float*)d_in[7];
  const float* u2a_b1 = (const float*)d_in[8];
  const float* u2a_w2 = (const float*)d_in[9];
  const float* u2a_b2 = (const float*)d_in[10];
  const float* ue_wih = (const float*)d_in[11];
  const float* ue_bih = (const float*)d_in[12];
  const float* ue_whh = (const float*)d_in[13];
  const float* ue_bhh = (const float*)d_in[14];
  const float* ap_wih = (const float*)d_in[15];
  const float* ap_bih = (const float*)d_in[16];
  const float* ap_whh = (const float*)d_in[17];
  const float* ap_bhh = (const float*)d_in[18];
  const float* ed_w1  = (const float*)d_in[19];
  const float* ed_b1  = (const float*)d_in[20];
  const float* ed_w2  = (const float*)d_in[21];
  const float* ed_b2  = (const float*)d_in[22];

  // workspace layout
  bf16_t* wb      = (bf16_t*)d_ws;
  bf16_t* wa1     = wb;                 // a2u_w1 (256x512)
  bf16_t* wa2     = wa1 + 131072;       // a2u_w2 (256x256)
  bf16_t* wu1     = wa2 + 65536;        // u2a_w1 (256x512)
  bf16_t* wu2     = wu1 + 131072;       // u2a_w2
  bf16_t* wih_ue  = wu2 + 65536;        // (768x256)
  bf16_t* whh_ue  = wih_ue + 196608;
  bf16_t* wih_ap  = whh_ue + 196608;
  bf16_t* whh_ap  = wih_ap + 196608;
  bf16_t* wed1    = whh_ap + 196608;    // ed_w1 (256x768)
  bf16_t* wed2    = wed1 + 196608;      // ed_w2
  float* fbase = (float*)((char*)d_ws + 2883584);
  float* m_ue = fbase;                  // 524288
  float* m_ap = m_ue + 524288;          // 1048576
  float* p_ap = m_ap + 1048576;         // 1048576
  float* p_ue = p_ap + 1048576;         // 524288
  float* q_ue = p_ue + 524288;          // 524288
  float* q_ap = q_ue + 524288;          // 1048576

  float* out      = (float*)d_out;
  float* hue_new  = out;                // 524288
  float* hap_new  = out + 524288;       // 1048576
  float* e_new    = out + 1572864;      // 33554432

  prep_kernel<<<7680, 256, 0, stream>>>(a2u_w1, a2u_w2, u2a_w1, u2a_w2,
                                        ue_wih, ue_whh, ap_wih, ap_whh,
                                        ed_w1, ed_w2, a2u_b2, wb, m_ue);
  proj_kernel<512><<<128, 256, 0, stream>>>(h_ap, wa1, a2u_b1, p_ap);
  proj_kernel<512><<<64, 256, 0, stream>>>(h_ue, wu1, u2a_b1, p_ue);
  phaseA_kernel<<<1024, 256, 0, stream>>>(e, p_ap, p_ue,
                                          wa1 + 256, wa2, wu1 + 256, wu2,
                                          u2a_b2, m_ue, m_ap);
  gru_kernel<<<64, 256, 0, stream>>>(m_ue, h_ue, wih_ue, whh_ue, ue_bih, ue_bhh, hue_new);
  gru_kernel<<<128, 256, 0, stream>>>(m_ap, h_ap, wih_ap, whh_ap, ap_bih, ap_bhh, hap_new);
  proj_kernel<768><<<64, 256, 0, stream>>>(hue_new, wed1, ed_b1, q_ue);
  proj_kernel<768><<<128, 256, 0, stream>>>(hap_new, wed1 + 256, nullptr, q_ap);
  phaseC_kernel<<<4096, 256, 0, stream>>>(e, q_ue, q_ap, wed1 + 512, wed2, ed_b2, e_new);
}